// Round 4
// baseline (481.295 us; speedup 1.0000x reference)
//
#include <hip/hip_runtime.h>
#include <hip/hip_bf16.h>
#include <cstdint>
#include <cstddef>

#define N_LEVELS   16
#define LOG2_T     19
#define TABLE_SIZE (1u << LOG2_T)
#define HASH_MASK  (TABLE_SIZE - 1u)
#define PRIME1     2654435761u

#define TPB 256
#define BT  64          // points per block

#define SORT_RES 512
#define NBINS    (SORT_RES * SORT_RES)

typedef __attribute__((ext_vector_type(8))) short short8;
typedef __attribute__((ext_vector_type(4))) float floatx4;
typedef __attribute__((ext_vector_type(2))) float f32x2;

// floor(16 * (2^(1/3))^l) in fp32 lands exactly on these integers
__device__ __constant__ float c_res[N_LEVELS] = {
    16.f, 20.f, 25.f, 32.f, 40.f, 50.f, 64.f, 80.f,
    101.f, 128.f, 161.f, 203.f, 256.f, 322.f, 406.f, 512.f
};

__device__ __forceinline__ unsigned short f2bf(float x) {
    union { float f; uint32_t u; } v; v.f = x;
    const uint32_t u = v.u;
    return (unsigned short)((u + 0x7fffu + ((u >> 16) & 1u)) >> 16);  // RNE
}

__device__ __forceinline__ uint32_t pk_bf16(float a, float b) {
#if __has_builtin(__builtin_amdgcn_cvt_pk_bf16_f32)
    typedef __attribute__((ext_vector_type(2))) __bf16 bf16x2;
    bf16x2 v = __builtin_amdgcn_cvt_pk_bf16_f32(a, b);
    uint32_t u; __builtin_memcpy(&u, &v, 4); return u;
#else
    return (uint32_t)f2bf(a) | ((uint32_t)f2bf(b) << 16);
#endif
}

// ---- XOR-swizzled LDS byte offsets (16B granules spread by row&7) ----
__device__ __forceinline__ int fswz(int row, int cb) {   // feat: 128 B/row
    return (row << 7) + (cb ^ ((row & 7) << 4));
}
__device__ __forceinline__ int hswz(int row, int cb) {   // h: 512 B/row
    return (row << 9) + (cb ^ ((row & 7) << 4));
}

// ---------------- spatial counting sort ----------------
// Bin key is ANY consistent spatial function — it does not affect numerics,
// only the memory locality of the hash-grid gathers (hash = ux ^ uy*P is the
// identity in ux, so consecutive bx with equal by -> consecutive table lines).
// One sort bin = one finest-level (res=512) cell.
__device__ __forceinline__ int bin_of(float2 c) {
    const float x = fminf(fmaxf(c.x, -1.f), 1.f);
    const float y = fminf(fmaxf(c.y, -1.f), 1.f);
    const int bx = (int)fminf((x + 1.0f) * 256.0f, 511.0f);
    const int by = (int)fminf((y + 1.0f) * 256.0f, 511.0f);
    return by * SORT_RES + bx;
}

__global__ void k_zero(uint32_t* __restrict__ p) {
    const int i = blockIdx.x * blockDim.x + threadIdx.x;
    uint4 z = {0u, 0u, 0u, 0u};
    *(uint4*)(p + i * 4) = z;
}

__global__ void k_hist(const float2* __restrict__ xy, uint32_t* __restrict__ hist, int n) {
    const int i = blockIdx.x * blockDim.x + threadIdx.x;
    if (i >= n) return;
    atomicAdd(hist + bin_of(xy[i]), 1u);
}

// 256 blocks x 256 threads; each block scans its 1024 bins in place to
// group-local exclusive offsets, writes the group total to sums[block].
__global__ void k_scan1(uint32_t* __restrict__ hist, uint32_t* __restrict__ sums) {
    __shared__ uint32_t lds[256];
    const int t = threadIdx.x;
    const int base = blockIdx.x * 1024 + t * 4;
    uint4 v = *(uint4*)(hist + base);
    const uint32_t s = v.x + v.y + v.z + v.w;
    lds[t] = s;
    __syncthreads();
    #pragma unroll
    for (int off = 1; off < 256; off <<= 1) {
        const uint32_t val = lds[t];
        const uint32_t add = (t >= off) ? lds[t - off] : 0u;
        __syncthreads();
        lds[t] = val + add;
        __syncthreads();
    }
    const uint32_t incl = lds[t];
    const uint32_t excl = incl - s;
    uint4 o;
    o.x = excl;
    o.y = excl + v.x;
    o.z = excl + v.x + v.y;
    o.w = excl + v.x + v.y + v.z;
    *(uint4*)(hist + base) = o;
    if (t == 255) sums[blockIdx.x] = incl;
}

// 1 block x 256 threads: exclusive scan of the 256 group sums, in place.
__global__ void k_scan2(uint32_t* __restrict__ sums) {
    __shared__ uint32_t lds[256];
    const int t = threadIdx.x;
    const uint32_t s = sums[t];
    lds[t] = s;
    __syncthreads();
    #pragma unroll
    for (int off = 1; off < 256; off <<= 1) {
        const uint32_t val = lds[t];
        const uint32_t add = (t >= off) ? lds[t - off] : 0u;
        __syncthreads();
        lds[t] = val + add;
        __syncthreads();
    }
    sums[t] = lds[t] - s;   // exclusive
}

__global__ void k_scatter(const float2* __restrict__ xy, uint32_t* __restrict__ hist,
                          const uint32_t* __restrict__ sums, int* __restrict__ perm,
                          float2* __restrict__ sxy, int n) {
    const int i = blockIdx.x * blockDim.x + threadIdx.x;
    if (i >= n) return;
    const float2 c = xy[i];
    const int b = bin_of(c);
    const uint32_t loc = atomicAdd(hist + b, 1u);     // hist holds group-local offsets
    const uint32_t pos = sums[b >> 10] + loc;
    perm[pos] = i;
    sxy[pos] = c;
}

// ---------------- weight packing into MFMA fragments ----------------
// Fragment for (tile, ktile): lane (q=l>>4, r=l&15) holds W[k = kt*32 + q*8 + j][col = tile*16 + r].
__global__ void pack_weights(const float* __restrict__ W0,
                             const float* __restrict__ W1,
                             const float* __restrict__ W2,
                             unsigned short* __restrict__ ws)
{
    const int f = blockIdx.x;       // 0..167
    const int lane = threadIdx.x;   // 0..63
    const int q = lane >> 4, r = lane & 15;
    int layer, kt, nt;
    if (f < 32)       { layer = 0; kt = f >> 4;        nt = f & 15; }
    else if (f < 160) { layer = 1; kt = (f - 32) >> 4; nt = (f - 32) & 15; }
    else              { layer = 2; kt = f - 160;       nt = 0; }
    unsigned short vals[8];
    #pragma unroll
    for (int j = 0; j < 8; ++j) {
        const int k = kt * 32 + q * 8 + j;
        const int n = nt * 16 + r;
        float v = 0.f;
        if (layer == 0) {
            // feat order: [enc0..enc31, x, y, zeros]; original W0 rows: [x, y, enc0..enc31]
            if (k < 32)       v = W0[(2 + k) * 256 + n];
            else if (k == 32) v = W0[0 * 256 + n];
            else if (k == 33) v = W0[1 * 256 + n];
        } else if (layer == 1) {
            v = W1[k * 256 + n];
        } else {
            if (n < 3) v = W2[k * 3 + n];
        }
        vals[j] = f2bf(v);
    }
    uint4 pk;
    pk.x = (uint32_t)vals[0] | ((uint32_t)vals[1] << 16);
    pk.y = (uint32_t)vals[2] | ((uint32_t)vals[3] << 16);
    pk.z = (uint32_t)vals[4] | ((uint32_t)vals[5] << 16);
    pk.w = (uint32_t)vals[6] | ((uint32_t)vals[7] << 16);
    *(uint4*)(ws + (size_t)f * 1024 + lane * 8) = pk;
}

// ---------------- fused encoding + MLP ----------------
__global__ __launch_bounds__(TPB, 4)
void fused_ngp_mlp(const float2* __restrict__ xy,
                   const int* __restrict__ perm,    // nullptr -> identity
                   const float* __restrict__ emb,
                   const unsigned short* __restrict__ wpack,
                   const float* __restrict__ b0,
                   const float* __restrict__ b1,
                   const float* __restrict__ b2,
                   float* __restrict__ out, int npoints)
{
    // bf16 feature tile [BT][64] (XOR-swizzled rows): [enc0..31, x, y, 0-pad..63]
    __shared__ __attribute__((aligned(16))) unsigned char feat[BT * 128];   // 8 KB
    // bf16 hidden tile [BT][256] (XOR-swizzled rows): h0, then h1; [point][neuron]
    __shared__ __attribute__((aligned(16))) unsigned char h[BT * 512];      // 32 KB

    const int t = threadIdx.x;
    // XCD-aware bijective swizzle: sorted points are spatially contiguous, so
    // keeping consecutive tiles on one XCD makes the shared table lines
    // L2-resident across neighboring blocks.
    int wg = blockIdx.x;
    const int nwg = gridDim.x;
    if ((nwg & 7) == 0) wg = (wg & 7) * (nwg >> 3) + (wg >> 3);
    const int p0 = wg * BT;
    const int wave = t >> 6;
    const int lane = t & 63;
    const int q = lane >> 4, r = lane & 15;

    // ---------- phase 1a: x,y + zero fill (bytes 64..127 of each feat row) ----------
    {
        const int p = t >> 2;          // 0..63
        const int sg = t & 3;
        const int gp = p0 + p;
        float x = 0.f, y = 0.f;
        if (gp < npoints) {
            const float2 c = xy[gp];
            x = fminf(fmaxf(c.x, -1.f), 1.f);
            y = fminf(fmaxf(c.y, -1.f), 1.f);
        }
        uint4 z = {0u, 0u, 0u, 0u};
        if (sg == 0) z.x = pk_bf16(x, y);
        *(uint4*)(feat + fswz(p, 64 + 16 * sg)) = z;
    }

    // ---------- phase 1b: hash-grid gathers, wave-uniform level group ----------
    {
        const int g = wave;            // level group (wave-uniform)
        const int p = lane;
        const int gp = p0 + p;
        float x = 0.f, y = 0.f;
        if (gp < npoints) {
            const float2 c = xy[gp];
            x = fminf(fmaxf(c.x, -1.f), 1.f);
            y = fminf(fmaxf(c.y, -1.f), 1.f);
        }
        float wxa[4], wya[4];
        f32x2 e[4][4];
        const f32x2* emb2 = (const f32x2*)emb;
        #pragma unroll
        for (int i = 0; i < 4; ++i) {
            const int l = 4 * g + i;
            const float res  = c_res[l];
            const float grid = 2.0f / res;             // IEEE div (matches ref)
            const float invg = res * 0.5f;             // exact
            const float tx = (x + 1.0f) / grid;        // IEEE div feeds floor -> exact cell match
            const float ty = (y + 1.0f) / grid;
            const int bx = (int)floorf(tx);
            const int by = (int)floorf(ty);
            const float vx = (float)bx * grid - 1.0f;
            const float vy = (float)by * grid - 1.0f;
            wxa[i] = (x - vx) * invg;
            wya[i] = (y - vy) * invg;
            const f32x2* tab = emb2 + (size_t)l * TABLE_SIZE;
            const uint32_t ux0 = (uint32_t)bx, ux1 = (uint32_t)(bx + 1);
            const uint32_t hy0 = (uint32_t)by * PRIME1;
            const uint32_t hy1 = (uint32_t)(by + 1) * PRIME1;
            e[i][0] = tab[(ux0 ^ hy0) & HASH_MASK];
            e[i][1] = tab[(ux0 ^ hy1) & HASH_MASK];
            e[i][2] = tab[(ux1 ^ hy0) & HASH_MASK];
            e[i][3] = tab[(ux1 ^ hy1) & HASH_MASK];
        }
        uint32_t vv[4];
        #pragma unroll
        for (int i = 0; i < 4; ++i) {
            const float wx = wxa[i], wy = wya[i];
            const float owx = 1.f - wx, owy = 1.f - wy;
            const float f0 = (e[i][0].x * owx + e[i][2].x * wx) * owy
                           + (e[i][1].x * owx + e[i][3].x * wx) * wy;
            const float f1 = (e[i][0].y * owx + e[i][2].y * wx) * owy
                           + (e[i][1].y * owx + e[i][3].y * wx) * wy;
            vv[i] = pk_bf16(f0, f1);
        }
        uint4 v; v.x = vv[0]; v.y = vv[1]; v.z = vv[2]; v.w = vv[3];
        *(uint4*)(feat + fswz(p, 16 * g)) = v;   // one 16 B write: levels 4g..4g+3
    }
    __syncthreads();

    const unsigned short* w0p = wpack;
    const unsigned short* w1p = wpack + 32 * 1024;
    const unsigned short* w2p = wpack + 160 * 1024;

    // ---------- phase 2: layer 0 (K=64 padded), W^T x feat^T -> h0[point][neuron] ----------
    {
        floatx4 acc[4][4];   // [mti (neuron tile)][nt (point tile)]
        #pragma unroll
        for (int mti = 0; mti < 4; ++mti)
            #pragma unroll
            for (int nt = 0; nt < 4; ++nt)
                acc[mti][nt] = floatx4{0.f, 0.f, 0.f, 0.f};
        #pragma unroll
        for (int kt = 0; kt < 2; ++kt) {
            short8 a[4], b[4];
            #pragma unroll
            for (int mti = 0; mti < 4; ++mti)
                a[mti] = *(const short8*)(w0p + (size_t)(kt * 16 + wave * 4 + mti) * 1024 + lane * 8);
            #pragma unroll
            for (int nt = 0; nt < 4; ++nt)
                b[nt] = *(const short8*)(feat + fswz(16 * nt + r, 64 * kt + 16 * q));
            #pragma unroll
            for (int mti = 0; mti < 4; ++mti)
                #pragma unroll
                for (int nt = 0; nt < 4; ++nt)
                    acc[mti][nt] = __builtin_amdgcn_mfma_f32_16x16x32_bf16(a[mti], b[nt], acc[mti][nt], 0, 0, 0);
        }
        // C[m=neuron=(wave*4+mti)*16+4q+reg][n=point=16nt+r]
        #pragma unroll
        for (int mti = 0; mti < 4; ++mti) {
            const int col = (wave * 4 + mti) * 16 + 4 * q;
            const float4 bias = *(const float4*)&b0[col];
            #pragma unroll
            for (int nt = 0; nt < 4; ++nt) {
                const floatx4 a = acc[mti][nt];
                uint2 v;
                v.x = pk_bf16(fmaxf(a[0] + bias.x, 0.f), fmaxf(a[1] + bias.y, 0.f));
                v.y = pk_bf16(fmaxf(a[2] + bias.z, 0.f), fmaxf(a[3] + bias.w, 0.f));
                *(uint2*)(h + hswz(16 * nt + r, 2 * col)) = v;
            }
        }
    }
    __syncthreads();

    // ---------- phase 3: layer 1 (256 -> 256) ----------
    {
        floatx4 acc[4][4];
        #pragma unroll
        for (int mti = 0; mti < 4; ++mti)
            #pragma unroll
            for (int nt = 0; nt < 4; ++nt)
                acc[mti][nt] = floatx4{0.f, 0.f, 0.f, 0.f};
        #pragma unroll 2
        for (int kt = 0; kt < 8; ++kt) {
            short8 a[4], b[4];
            #pragma unroll
            for (int mti = 0; mti < 4; ++mti)
                a[mti] = *(const short8*)(w1p + (size_t)(kt * 16 + wave * 4 + mti) * 1024 + lane * 8);
            #pragma unroll
            for (int nt = 0; nt < 4; ++nt)
                b[nt] = *(const short8*)(h + hswz(16 * nt + r, 64 * kt + 16 * q));
            #pragma unroll
            for (int mti = 0; mti < 4; ++mti)
                #pragma unroll
                for (int nt = 0; nt < 4; ++nt)
                    acc[mti][nt] = __builtin_amdgcn_mfma_f32_16x16x32_bf16(a[mti], b[nt], acc[mti][nt], 0, 0, 0);
        }
        __syncthreads();   // all reads of h0 done before overwrite
        #pragma unroll
        for (int mti = 0; mti < 4; ++mti) {
            const int col = (wave * 4 + mti) * 16 + 4 * q;
            const float4 bias = *(const float4*)&b1[col];
            #pragma unroll
            for (int nt = 0; nt < 4; ++nt) {
                const floatx4 a = acc[mti][nt];
                uint2 v;
                v.x = pk_bf16(fmaxf(a[0] + bias.x, 0.f), fmaxf(a[1] + bias.y, 0.f));
                v.y = pk_bf16(fmaxf(a[2] + bias.z, 0.f), fmaxf(a[3] + bias.w, 0.f));
                *(uint2*)(h + hswz(16 * nt + r, 2 * col)) = v;
            }
        }
    }
    __syncthreads();

    // ---------- phase 4: layer 2 (256 -> 3), sigmoid, store ----------
    {
        floatx4 acc = floatx4{0.f, 0.f, 0.f, 0.f};
        #pragma unroll
        for (int kt = 0; kt < 8; ++kt) {
            const short8 a = *(const short8*)(w2p + (size_t)kt * 1024 + lane * 8);
            const short8 b = *(const short8*)(h + hswz(16 * wave + r, 64 * kt + 16 * q));
            acc = __builtin_amdgcn_mfma_f32_16x16x32_bf16(a, b, acc, 0, 0, 0);
        }
        // C[m=4q+reg][n=16*wave+r]: only q==0, reg<3 are real outputs
        if (q == 0) {
            const int gp = p0 + 16 * wave + r;
            if (gp < npoints) {
                const int oi = perm ? perm[gp] : gp;
                #pragma unroll
                for (int reg = 0; reg < 3; ++reg) {
                    const float s = acc[reg] + b2[reg];
                    out[(size_t)oi * 3 + reg] = 1.f / (1.f + expf(-s));
                }
            }
        }
    }
}

extern "C" void kernel_launch(void* const* d_in, const int* in_sizes, int n_in,
                              void* d_out, int out_size, void* d_ws, size_t ws_size,
                              hipStream_t stream) {
    const float* coord = (const float*)d_in[0];
    const float* emb   = (const float*)d_in[1];
    const float* W0    = (const float*)d_in[2];
    const float* b0    = (const float*)d_in[3];
    const float* W1    = (const float*)d_in[4];
    const float* b1    = (const float*)d_in[5];
    const float* W2    = (const float*)d_in[6];
    const float* b2    = (const float*)d_in[7];
    float* out = (float*)d_out;
    unsigned char* ws = (unsigned char*)d_ws;

    const int npoints = in_sizes[0] / 2;
    const int blocks  = (npoints + BT - 1) / BT;

    // workspace layout (16B-aligned sections)
    const size_t W_BYTES   = 168 * 1024 * 2;                    // 344064 (16-aligned)
    const size_t off_hist  = W_BYTES;                           // NBINS u32 (1 MB)
    const size_t off_sums  = off_hist + (size_t)NBINS * 4;      // 256 u32
    const size_t off_perm  = off_sums + 1024;                   // npoints i32
    size_t off_sxy = off_perm + (size_t)npoints * 4;
    off_sxy = (off_sxy + 15) & ~(size_t)15;                     // align
    const size_t required  = off_sxy + (size_t)npoints * 8;

    unsigned short* wp = (unsigned short*)(ws);
    hipLaunchKernelGGL(pack_weights, dim3(168), dim3(64), 0, stream, W0, W1, W2, wp);

    if (ws_size >= required && npoints > 0) {
        uint32_t* hist = (uint32_t*)(ws + off_hist);
        uint32_t* sums = (uint32_t*)(ws + off_sums);
        int*      perm = (int*)(ws + off_perm);
        float2*   sxy  = (float2*)(ws + off_sxy);
        const float2* cxy = (const float2*)coord;

        const int pb = (npoints + 255) / 256;
        hipLaunchKernelGGL(k_zero,    dim3(NBINS / 1024), dim3(256), 0, stream, hist);
        hipLaunchKernelGGL(k_hist,    dim3(pb),  dim3(256), 0, stream, cxy, hist, npoints);
        hipLaunchKernelGGL(k_scan1,   dim3(256), dim3(256), 0, stream, hist, sums);
        hipLaunchKernelGGL(k_scan2,   dim3(1),   dim3(256), 0, stream, sums);
        hipLaunchKernelGGL(k_scatter, dim3(pb),  dim3(256), 0, stream, cxy, hist, sums, perm, sxy, npoints);
        hipLaunchKernelGGL(fused_ngp_mlp, dim3(blocks), dim3(TPB), 0, stream,
                           sxy, perm, emb, wp, b0, b1, b2, out, npoints);
    } else {
        hipLaunchKernelGGL(fused_ngp_mlp, dim3(blocks), dim3(TPB), 0, stream,
                           (const float2*)coord, (const int*)nullptr, emb, wp, b0, b1, b2, out, npoints);
    }
}

// Round 5
// 355.109 us; speedup vs baseline: 1.3553x; 1.3553x over previous
//
#include <hip/hip_runtime.h>
#include <hip/hip_bf16.h>
#include <cstdint>
#include <cstddef>

#define N_LEVELS   16
#define LOG2_T     19
#define TABLE_SIZE (1u << LOG2_T)
#define HASH_MASK  (TABLE_SIZE - 1u)
#define PRIME1     2654435761u

#define TPB 256
#define BT  64          // points per block

typedef __attribute__((ext_vector_type(8))) short short8;
typedef __attribute__((ext_vector_type(4))) float floatx4;
typedef __attribute__((ext_vector_type(2))) float f32x2;

// floor(16 * (2^(1/3))^l) in fp32 lands exactly on these integers
__device__ __forceinline__ constexpr float resf(int l) {
    constexpr float r[N_LEVELS] = {
        16.f, 20.f, 25.f, 32.f, 40.f, 50.f, 64.f, 80.f,
        101.f, 128.f, 161.f, 203.f, 256.f, 322.f, 406.f, 512.f
    };
    return r[l];
}

__device__ __forceinline__ unsigned short f2bf(float x) {
    union { float f; uint32_t u; } v; v.f = x;
    const uint32_t u = v.u;
    return (unsigned short)((u + 0x7fffu + ((u >> 16) & 1u)) >> 16);  // RNE
}

__device__ __forceinline__ uint32_t pk_bf16(float a, float b) {
#if __has_builtin(__builtin_amdgcn_cvt_pk_bf16_f32)
    typedef __attribute__((ext_vector_type(2))) __bf16 bf16x2;
    bf16x2 v = __builtin_amdgcn_cvt_pk_bf16_f32(a, b);
    uint32_t u; __builtin_memcpy(&u, &v, 4); return u;
#else
    return (uint32_t)f2bf(a) | ((uint32_t)f2bf(b) << 16);
#endif
}

// ---- XOR-swizzled LDS byte offsets ----
// feat: 128 B/row. 16B-granule spread by row&7 (8 slots/row is the max).
__device__ __forceinline__ int fswz(int row, int cb) {
    return (row << 7) + (cb ^ ((row & 7) << 4));
}
// h: 512 B/row. Mask (c<<4)^(c<<6), c=row&7: the B-frag read pattern
// (lanes span 16 rows x 4 q-slots) maps to slot (4kt+q) ^ (c^4c); d^4d for
// d!=0 never lies in {1,2,3}, so (q,c)->slot is injective: 32 slots, 2
// lanes each (r vs r+8) -> 2-way (free, m136). Old (c<<4) mask collided q
// with r&3 -> 8-way on every MFMA b-read (the 2e7 SQ_LDS_BANK_CONFLICT).
__device__ __forceinline__ int hswz(int row, int cb) {
    const int c = row & 7;
    return (row << 9) + (cb ^ ((c << 4) ^ (c << 6)));
}

// ---------------- weight packing into MFMA fragments ----------------
// Fragment for (tile, ktile): lane (q=l>>4, r=l&15) holds W[k = kt*32 + q*8 + j][col = tile*16 + r].
__global__ void pack_weights(const float* __restrict__ W0,
                             const float* __restrict__ W1,
                             const float* __restrict__ W2,
                             unsigned short* __restrict__ ws)
{
    const int f = blockIdx.x;       // 0..167
    const int lane = threadIdx.x;   // 0..63
    const int q = lane >> 4, r = lane & 15;
    int layer, kt, nt;
    if (f < 32)       { layer = 0; kt = f >> 4;        nt = f & 15; }
    else if (f < 160) { layer = 1; kt = (f - 32) >> 4; nt = (f - 32) & 15; }
    else              { layer = 2; kt = f - 160;       nt = 0; }
    unsigned short vals[8];
    #pragma unroll
    for (int j = 0; j < 8; ++j) {
        const int k = kt * 32 + q * 8 + j;
        const int n = nt * 16 + r;
        float v = 0.f;
        if (layer == 0) {
            // feat order: [enc0..enc31, x, y, zeros]; original W0 rows: [x, y, enc0..enc31]
            if (k < 32)       v = W0[(2 + k) * 256 + n];
            else if (k == 32) v = W0[0 * 256 + n];
            else if (k == 33) v = W0[1 * 256 + n];
        } else if (layer == 1) {
            v = W1[k * 256 + n];
        } else {
            if (n < 3) v = W2[k * 3 + n];
        }
        vals[j] = f2bf(v);
    }
    uint4 pk;
    pk.x = (uint32_t)vals[0] | ((uint32_t)vals[1] << 16);
    pk.y = (uint32_t)vals[2] | ((uint32_t)vals[3] << 16);
    pk.z = (uint32_t)vals[4] | ((uint32_t)vals[5] << 16);
    pk.w = (uint32_t)vals[6] | ((uint32_t)vals[7] << 16);
    *(uint4*)(ws + (size_t)f * 1024 + lane * 8) = pk;
}

// ---- phase-1 encode: 4 levels of compile-time group G for one point ----
// All level constants fold to literals; pow2-res levels (16,32,64,128,256,512)
// get their IEEE div legally strength-reduced to an exact multiply.
template<int G>
__device__ __forceinline__ uint4 encode4(float x, float y, const char* __restrict__ ebase)
{
    uint32_t vv[4];
    #pragma unroll
    for (int i = 0; i < 4; ++i) {
        const int l = 4 * G + i;
        const float res  = resf(l);
        const float grid = 2.0f / res;             // constexpr IEEE div (matches ref)
        const float invg = res * 0.5f;             // exact
        const float tx = (x + 1.0f) / grid;        // div-by-constant; exact mul for pow2
        const float ty = (y + 1.0f) / grid;
        const int bx = (int)floorf(tx);
        const int by = (int)floorf(ty);
        const float wx = (x - ((float)bx * grid - 1.0f)) * invg;
        const float wy = (y - ((float)by * grid - 1.0f)) * invg;
        const uint32_t hy0 = (uint32_t)by * PRIME1;
        const uint32_t hy1 = hy0 + PRIME1;         // (by+1)*P mod 2^32
        const uint32_t ux0 = (uint32_t)bx;
        const uint32_t ux1 = ux0 + 1u;
        const uint32_t lb = (uint32_t)l << (LOG2_T + 3);   // level table byte base
        const f32x2 e00 = *(const f32x2*)(ebase + (lb + (((ux0 ^ hy0) & HASH_MASK) << 3)));
        const f32x2 e01 = *(const f32x2*)(ebase + (lb + (((ux0 ^ hy1) & HASH_MASK) << 3)));
        const f32x2 e10 = *(const f32x2*)(ebase + (lb + (((ux1 ^ hy0) & HASH_MASK) << 3)));
        const f32x2 e11 = *(const f32x2*)(ebase + (lb + (((ux1 ^ hy1) & HASH_MASK) << 3)));
        const float owx = 1.f - wx, owy = 1.f - wy;
        const float f0 = (e00.x * owx + e10.x * wx) * owy + (e01.x * owx + e11.x * wx) * wy;
        const float f1 = (e00.y * owx + e10.y * wx) * owy + (e01.y * owx + e11.y * wx) * wy;
        vv[i] = pk_bf16(f0, f1);
    }
    uint4 v; v.x = vv[0]; v.y = vv[1]; v.z = vv[2]; v.w = vv[3];
    return v;
}

// ---- epilogue: bias + relu + bf16 pack, via packed f32 ops ----
__device__ __forceinline__ uint2 bias_relu_pk(const floatx4 a, const float4 bias)
{
    const f32x2 z = {0.f, 0.f};
    f32x2 v01 = {a[0], a[1]};
    f32x2 v23 = {a[2], a[3]};
    const f32x2 b01 = {bias.x, bias.y};
    const f32x2 b23 = {bias.z, bias.w};
    v01 += b01;                                    // v_pk_add_f32
    v23 += b23;
    v01 = __builtin_elementwise_max(v01, z);       // v_pk_max_f32
    v23 = __builtin_elementwise_max(v23, z);
    uint2 r;
    r.x = pk_bf16(v01.x, v01.y);
    r.y = pk_bf16(v23.x, v23.y);
    return r;
}

// ---------------- fused encoding + MLP ----------------
__global__ __launch_bounds__(TPB, 4)
void fused_ngp_mlp(const float2* __restrict__ xy,
                   const float* __restrict__ emb,
                   const unsigned short* __restrict__ wpack,
                   const float* __restrict__ b0,
                   const float* __restrict__ b1,
                   const float* __restrict__ b2,
                   float* __restrict__ out, int npoints)
{
    // bf16 feature tile [BT][64] (XOR-swizzled rows): [enc0..31, x, y, 0-pad..63]
    __shared__ __attribute__((aligned(16))) unsigned char feat[BT * 128];   // 8 KB
    // bf16 hidden tile [BT][256] (XOR-swizzled rows): h0, then h1; [point][neuron]
    __shared__ __attribute__((aligned(16))) unsigned char h[BT * 512];      // 32 KB

    const int t = threadIdx.x;
    const int p0 = blockIdx.x * BT;
    const int wave = t >> 6;
    const int lane = t & 63;
    const int q = lane >> 4, r = lane & 15;

    // ---------- phase 1a: x,y + zero fill (bytes 64..127 of each feat row) ----------
    {
        const int p = t >> 2;          // 0..63
        const int sg = t & 3;
        const int gp = p0 + p;
        float x = 0.f, y = 0.f;
        if (gp < npoints) {
            const float2 c = xy[gp];
            x = fminf(fmaxf(c.x, -1.f), 1.f);
            y = fminf(fmaxf(c.y, -1.f), 1.f);
        }
        uint4 z = {0u, 0u, 0u, 0u};
        if (sg == 0) z.x = pk_bf16(x, y);
        *(uint4*)(feat + fswz(p, 64 + 16 * sg)) = z;
    }

    // ---------- phase 1b: hash-grid gathers, wave-uniform compile-time level group ----------
    {
        const int p = lane;
        const int gp = p0 + p;
        float x = 0.f, y = 0.f;
        if (gp < npoints) {
            const float2 c = xy[gp];
            x = fminf(fmaxf(c.x, -1.f), 1.f);
            y = fminf(fmaxf(c.y, -1.f), 1.f);
        }
        const char* ebase = (const char*)emb;
        uint4 v;
        switch (wave) {
            case 0:  v = encode4<0>(x, y, ebase); break;
            case 1:  v = encode4<1>(x, y, ebase); break;
            case 2:  v = encode4<2>(x, y, ebase); break;
            default: v = encode4<3>(x, y, ebase); break;
        }
        *(uint4*)(feat + fswz(p, 16 * wave)) = v;   // one 16 B write: levels 4w..4w+3
    }
    __syncthreads();

    const unsigned short* w0p = wpack;
    const unsigned short* w1p = wpack + 32 * 1024;
    const unsigned short* w2p = wpack + 160 * 1024;

    // ---------- phase 2: layer 0 (K=64 padded), W^T x feat^T -> h0[point][neuron] ----------
    {
        floatx4 acc[4][4];   // [mti (neuron tile)][nt (point tile)]
        #pragma unroll
        for (int mti = 0; mti < 4; ++mti)
            #pragma unroll
            for (int nt = 0; nt < 4; ++nt)
                acc[mti][nt] = floatx4{0.f, 0.f, 0.f, 0.f};
        #pragma unroll
        for (int kt = 0; kt < 2; ++kt) {
            short8 a[4], b[4];
            #pragma unroll
            for (int mti = 0; mti < 4; ++mti)
                a[mti] = *(const short8*)(w0p + (size_t)(kt * 16 + wave * 4 + mti) * 1024 + lane * 8);
            #pragma unroll
            for (int nt = 0; nt < 4; ++nt)
                b[nt] = *(const short8*)(feat + fswz(16 * nt + r, 64 * kt + 16 * q));
            #pragma unroll
            for (int mti = 0; mti < 4; ++mti)
                #pragma unroll
                for (int nt = 0; nt < 4; ++nt)
                    acc[mti][nt] = __builtin_amdgcn_mfma_f32_16x16x32_bf16(a[mti], b[nt], acc[mti][nt], 0, 0, 0);
        }
        // C[m=neuron=(wave*4+mti)*16+4q+reg][n=point=16nt+r]
        #pragma unroll
        for (int mti = 0; mti < 4; ++mti) {
            const int col = (wave * 4 + mti) * 16 + 4 * q;
            const float4 bias = *(const float4*)&b0[col];
            #pragma unroll
            for (int nt = 0; nt < 4; ++nt) {
                const uint2 v = bias_relu_pk(acc[mti][nt], bias);
                *(uint2*)(h + hswz(16 * nt + r, 2 * col)) = v;
            }
        }
    }
    __syncthreads();

    // ---------- phase 3: layer 1 (256 -> 256) ----------
    {
        floatx4 acc[4][4];
        #pragma unroll
        for (int mti = 0; mti < 4; ++mti)
            #pragma unroll
            for (int nt = 0; nt < 4; ++nt)
                acc[mti][nt] = floatx4{0.f, 0.f, 0.f, 0.f};
        #pragma unroll 2
        for (int kt = 0; kt < 8; ++kt) {
            short8 a[4], b[4];
            #pragma unroll
            for (int mti = 0; mti < 4; ++mti)
                a[mti] = *(const short8*)(w1p + (size_t)(kt * 16 + wave * 4 + mti) * 1024 + lane * 8);
            #pragma unroll
            for (int nt = 0; nt < 4; ++nt)
                b[nt] = *(const short8*)(h + hswz(16 * nt + r, 64 * kt + 16 * q));
            #pragma unroll
            for (int mti = 0; mti < 4; ++mti)
                #pragma unroll
                for (int nt = 0; nt < 4; ++nt)
                    acc[mti][nt] = __builtin_amdgcn_mfma_f32_16x16x32_bf16(a[mti], b[nt], acc[mti][nt], 0, 0, 0);
        }
        __syncthreads();   // all reads of h0 done before overwrite
        #pragma unroll
        for (int mti = 0; mti < 4; ++mti) {
            const int col = (wave * 4 + mti) * 16 + 4 * q;
            const float4 bias = *(const float4*)&b1[col];
            #pragma unroll
            for (int nt = 0; nt < 4; ++nt) {
                const uint2 v = bias_relu_pk(acc[mti][nt], bias);
                *(uint2*)(h + hswz(16 * nt + r, 2 * col)) = v;
            }
        }
    }
    __syncthreads();

    // ---------- phase 4: layer 2 (256 -> 3), sigmoid, store ----------
    {
        floatx4 acc = floatx4{0.f, 0.f, 0.f, 0.f};
        #pragma unroll
        for (int kt = 0; kt < 8; ++kt) {
            const short8 a = *(const short8*)(w2p + (size_t)kt * 1024 + lane * 8);
            const short8 b = *(const short8*)(h + hswz(16 * wave + r, 64 * kt + 16 * q));
            acc = __builtin_amdgcn_mfma_f32_16x16x32_bf16(a, b, acc, 0, 0, 0);
        }
        // C[m=4q+reg][n=16*wave+r]: only q==0, reg<3 are real outputs
        if (q == 0) {
            const int gp = p0 + 16 * wave + r;
            if (gp < npoints) {
                #pragma unroll
                for (int reg = 0; reg < 3; ++reg) {
                    const float s = acc[reg] + b2[reg];
                    out[(size_t)gp * 3 + reg] = 1.f / (1.f + expf(-s));
                }
            }
        }
    }
}

extern "C" void kernel_launch(void* const* d_in, const int* in_sizes, int n_in,
                              void* d_out, int out_size, void* d_ws, size_t ws_size,
                              hipStream_t stream) {
    const float* coord = (const float*)d_in[0];
    const float* emb   = (const float*)d_in[1];
    const float* W0    = (const float*)d_in[2];
    const float* b0    = (const float*)d_in[3];
    const float* W1    = (const float*)d_in[4];
    const float* b1    = (const float*)d_in[5];
    const float* W2    = (const float*)d_in[6];
    const float* b2    = (const float*)d_in[7];
    float* out = (float*)d_out;
    unsigned short* ws = (unsigned short*)d_ws;

    const int npoints = in_sizes[0] / 2;
    const int blocks  = (npoints + BT - 1) / BT;

    hipLaunchKernelGGL(pack_weights, dim3(168), dim3(64), 0, stream, W0, W1, W2, ws);
    hipLaunchKernelGGL(fused_ngp_mlp, dim3(blocks), dim3(TPB), 0, stream,
                       (const float2*)coord, emb, ws, b0, b1, b2, out, npoints);
}